// Round 1
// baseline (360.561 us; speedup 1.0000x reference)
//
#include <hip/hip_runtime.h>

// HandcraftedPodExtractor: 3D cell binning + normalized feature vector.
// Input  x: (64, 65536, 6) fp32  [pos(3) | ori(3)] interleaved per point.
// Output  : (64, 640) fp32.
//
// ws layout:
//   [0,   256)            : per-batch bbox_max as uint bits (64 * 4B, padded)
//   [256, 256 + 163840)   : acc[B][64 cells][10 vals] fp32
//
// Numerics: cell assignment replicated bit-exactly vs reference:
// (p + bmax) / thick with IEEE '/', then *4.0f, trunc-to-int, clip. Cell
// centers k*0.25+0.125 are fp-exact. Accumulation order differs (atomics)
// but sums are smooth — well within threshold.

#define BATCH 64
#define NPTS 65536
#define FEAT 640          // 64 cells * 10 values
#define COPIES 16         // replicated LDS histograms (lane % 16)
#define CSTRIDE 17        // padded copy stride -> 16 distinct banks per slot

__device__ __forceinline__ void bin_point(float* h, int k,
                                          float px, float py, float pz,
                                          float ox, float oy, float oz,
                                          float bmax, float thick) {
    // pos_in_cube, IEEE division to match reference exactly
    float sx = (px + bmax) / thick;
    float sy = (py + bmax) / thick;
    float sz = (pz + bmax) / thick;
    int cx = (int)(sx * 4.0f); cx = cx < 0 ? 0 : (cx > 3 ? 3 : cx);
    int cy = (int)(sy * 4.0f); cy = cy < 0 ? 0 : (cy > 3 ? 3 : cy);
    int cz = (int)(sz * 4.0f); cz = cz < 0 ? 0 : (cz > 3 ? 3 : cz);
    int cell = (cx * 4 + cy) * 4 + cz;
    float offx = sx - (cx * 0.25f + 0.125f);
    float offy = sy - (cy * 0.25f + 0.125f);
    float offz = sz - (cz * 0.25f + 0.125f);
    // slot address: (cell*10 + j)*CSTRIDE + k
    int a = cell * (10 * CSTRIDE) + k;
    atomicAdd(&h[a + 0 * CSTRIDE], 1.0f);
    atomicAdd(&h[a + 1 * CSTRIDE], offx);
    atomicAdd(&h[a + 2 * CSTRIDE], offy);
    atomicAdd(&h[a + 3 * CSTRIDE], offz);
    atomicAdd(&h[a + 4 * CSTRIDE], ox * ox);
    atomicAdd(&h[a + 5 * CSTRIDE], ox * oy);
    atomicAdd(&h[a + 6 * CSTRIDE], ox * oz);
    atomicAdd(&h[a + 7 * CSTRIDE], oy * oy);
    atomicAdd(&h[a + 8 * CSTRIDE], oy * oz);
    atomicAdd(&h[a + 9 * CSTRIDE], oz * oz);
}

// Pass 1: per-batch max|pos|. grid (16, B) x 256.
__global__ __launch_bounds__(256) void k_bbox(const float* __restrict__ x,
                                              unsigned int* __restrict__ bbox) {
    int b = blockIdx.y;
    const float4* base = (const float4*)(x + (size_t)b * NPTS * 6);
    int tid = blockIdx.x * 256 + threadIdx.x;   // 4096 threads per batch
    float m = 0.0f;
    for (int i = tid; i < NPTS / 2; i += 4096) {
        float4 f0 = base[3 * i + 0];
        float4 f1 = base[3 * i + 1];
        float4 f2 = base[3 * i + 2];
        m = fmaxf(m, fabsf(f0.x)); m = fmaxf(m, fabsf(f0.y)); m = fmaxf(m, fabsf(f0.z));
        m = fmaxf(m, fabsf(f1.z)); m = fmaxf(m, fabsf(f1.w)); m = fmaxf(m, fabsf(f2.x));
    }
    for (int off = 32; off > 0; off >>= 1) m = fmaxf(m, __shfl_down(m, off, 64));
    __shared__ float s[4];
    if ((threadIdx.x & 63) == 0) s[threadIdx.x >> 6] = m;
    __syncthreads();
    if (threadIdx.x == 0) {
        m = fmaxf(fmaxf(s[0], s[1]), fmaxf(s[2], s[3]));
        atomicMax(&bbox[b], __float_as_uint(m));  // valid: all values >= 0
    }
}

// Pass 2: histogram into 16 replicated LDS copies, then global atomicAdd.
// grid (16, B) x 256. LDS = 640*17*4 = 43520 B -> 3 blocks/CU.
__global__ __launch_bounds__(256) void k_bin(const float* __restrict__ x,
                                             const unsigned int* __restrict__ bbox,
                                             float* __restrict__ acc) {
    __shared__ float h[FEAT * CSTRIDE];
    for (int i = threadIdx.x; i < FEAT * CSTRIDE; i += 256) h[i] = 0.0f;
    int b = blockIdx.y;
    float bmax = __uint_as_float(bbox[b]);
    float thick = fmaxf(2.0f * bmax, 1e-5f);
    __syncthreads();

    const float4* base = (const float4*)(x + (size_t)b * NPTS * 6);
    int tid = blockIdx.x * 256 + threadIdx.x;   // 4096 threads per batch
    int k = threadIdx.x & (COPIES - 1);
    for (int i = tid; i < NPTS / 2; i += 4096) {
        float4 f0 = base[3 * i + 0];
        float4 f1 = base[3 * i + 1];
        float4 f2 = base[3 * i + 2];
        bin_point(h, k, f0.x, f0.y, f0.z, f0.w, f1.x, f1.y, bmax, thick);
        bin_point(h, k, f1.z, f1.w, f2.x, f2.y, f2.z, f2.w, bmax, thick);
    }
    __syncthreads();
    for (int v = threadIdx.x; v < FEAT; v += 256) {
        float sum = 0.0f;
        #pragma unroll
        for (int c = 0; c < COPIES; ++c) sum += h[v * CSTRIDE + c];
        atomicAdd(&acc[b * FEAT + v], sum);
    }
}

// Pass 3: features + L2 normalize. grid B x 640 (one thread per feature).
__global__ __launch_bounds__(640) void k_final(const float* __restrict__ acc,
                                               float* __restrict__ out) {
    int b = blockIdx.x;
    int t = threadIdx.x;           // 0..639
    int cell = t / 10, j = t - cell * 10;
    float n = acc[b * FEAT + cell * 10];   // count for this cell
    float v = acc[b * FEAT + t];
    float fc = fmaxf(n, 1.0f);
    float up = 1.0f / sqrtf(fc);
    float val;
    if (j == 0)      val = 0.001f * n * up;
    else if (j < 4)  val = v * up;
    else             val = v / fc;

    // block reduction of sum(val^2) across 10 waves
    __shared__ float red[12];
    float s = val * val;
    for (int off = 32; off > 0; off >>= 1) s += __shfl_down(s, off, 64);
    if ((t & 63) == 0) red[t >> 6] = s;
    __syncthreads();
    if (t == 0) {
        float tot = 0.0f;
        #pragma unroll
        for (int w = 0; w < 10; ++w) tot += red[w];
        red[10] = fmaxf(sqrtf(tot), 1e-12f);
    }
    __syncthreads();
    out[b * FEAT + t] = val / red[10];
}

extern "C" void kernel_launch(void* const* d_in, const int* in_sizes, int n_in,
                              void* d_out, int out_size, void* d_ws, size_t ws_size,
                              hipStream_t stream) {
    const float* x = (const float*)d_in[0];
    float* out = (float*)d_out;
    unsigned int* bbox = (unsigned int*)d_ws;
    float* acc = (float*)((char*)d_ws + 256);

    // zero bbox + accumulators (ws is poisoned 0xAA before every launch)
    hipMemsetAsync(d_ws, 0, 256 + (size_t)BATCH * FEAT * 4, stream);

    dim3 grid(16, BATCH);
    k_bbox<<<grid, 256, 0, stream>>>(x, bbox);
    k_bin<<<grid, 256, 0, stream>>>(x, bbox, acc);
    k_final<<<BATCH, 640, 0, stream>>>(acc, out);
}

// Round 2
// 358.049 us; speedup vs baseline: 1.0070x; 1.0070x over previous
//
#include <hip/hip_runtime.h>

// HandcraftedPodExtractor: 3D cell binning + normalized feature vector.
// Input  x: (64, 65536, 6) fp32  [pos(3) | ori(3)] interleaved per point.
// Output  : (64, 640) fp32.
//
// R1 finding: plain atomicAdd(float) lowers to a CAS loop (no
// -munsafe-fp-atomics in harness flags) -> k_bin was 215us. Fix:
// unsafeAtomicAdd -> native ds_add_f32 / global_atomic_add_f32.
// Also replaced the 3 IEEE divides/point with one reciprocal per batch
// (<=1 ulp difference; cell flips only within 1 ulp of a bin boundary,
// ~1e-4 output perturbation vs 5.9e-3 threshold).
//
// ws layout:
//   [0,   256)            : per-batch bbox_max as uint bits (64 * 4B, padded)
//   [256, 256 + 163840)   : acc[B][64 cells][10 vals] fp32

#define BATCH 64
#define NPTS 65536
#define FEAT 640          // 64 cells * 10 values
#define COPIES 16         // replicated LDS histograms (lane % 16)
#define CSTRIDE 17        // padded copy stride -> 16 distinct banks per slot

__device__ __forceinline__ void bin_point(float* h, int k,
                                          float px, float py, float pz,
                                          float ox, float oy, float oz,
                                          float bmax, float inv_thick) {
    float sx = (px + bmax) * inv_thick;
    float sy = (py + bmax) * inv_thick;
    float sz = (pz + bmax) * inv_thick;
    int cx = (int)(sx * 4.0f); cx = cx < 0 ? 0 : (cx > 3 ? 3 : cx);
    int cy = (int)(sy * 4.0f); cy = cy < 0 ? 0 : (cy > 3 ? 3 : cy);
    int cz = (int)(sz * 4.0f); cz = cz < 0 ? 0 : (cz > 3 ? 3 : cz);
    int cell = (cx * 4 + cy) * 4 + cz;
    float offx = sx - (cx * 0.25f + 0.125f);
    float offy = sy - (cy * 0.25f + 0.125f);
    float offz = sz - (cz * 0.25f + 0.125f);
    int a = cell * (10 * CSTRIDE) + k;
    unsafeAtomicAdd(&h[a + 0 * CSTRIDE], 1.0f);
    unsafeAtomicAdd(&h[a + 1 * CSTRIDE], offx);
    unsafeAtomicAdd(&h[a + 2 * CSTRIDE], offy);
    unsafeAtomicAdd(&h[a + 3 * CSTRIDE], offz);
    unsafeAtomicAdd(&h[a + 4 * CSTRIDE], ox * ox);
    unsafeAtomicAdd(&h[a + 5 * CSTRIDE], ox * oy);
    unsafeAtomicAdd(&h[a + 6 * CSTRIDE], ox * oz);
    unsafeAtomicAdd(&h[a + 7 * CSTRIDE], oy * oy);
    unsafeAtomicAdd(&h[a + 8 * CSTRIDE], oy * oz);
    unsafeAtomicAdd(&h[a + 9 * CSTRIDE], oz * oz);
}

// Pass 1: per-batch max|pos|. grid (16, B) x 256.
__global__ __launch_bounds__(256) void k_bbox(const float* __restrict__ x,
                                              unsigned int* __restrict__ bbox) {
    int b = blockIdx.y;
    const float4* base = (const float4*)(x + (size_t)b * NPTS * 6);
    int tid = blockIdx.x * 256 + threadIdx.x;   // 4096 threads per batch
    float m = 0.0f;
    for (int i = tid; i < NPTS / 2; i += 4096) {
        float4 f0 = base[3 * i + 0];
        float4 f1 = base[3 * i + 1];
        float4 f2 = base[3 * i + 2];
        m = fmaxf(m, fabsf(f0.x)); m = fmaxf(m, fabsf(f0.y)); m = fmaxf(m, fabsf(f0.z));
        m = fmaxf(m, fabsf(f1.z)); m = fmaxf(m, fabsf(f1.w)); m = fmaxf(m, fabsf(f2.x));
    }
    for (int off = 32; off > 0; off >>= 1) m = fmaxf(m, __shfl_down(m, off, 64));
    __shared__ float s[4];
    if ((threadIdx.x & 63) == 0) s[threadIdx.x >> 6] = m;
    __syncthreads();
    if (threadIdx.x == 0) {
        m = fmaxf(fmaxf(s[0], s[1]), fmaxf(s[2], s[3]));
        atomicMax(&bbox[b], __float_as_uint(m));  // integer atomic: native
    }
}

// Pass 2: histogram into 16 replicated LDS copies, then global add.
// grid (16, B) x 256. LDS = 640*17*4 = 43520 B -> 3 blocks/CU.
__global__ __launch_bounds__(256) void k_bin(const float* __restrict__ x,
                                             const unsigned int* __restrict__ bbox,
                                             float* __restrict__ acc) {
    __shared__ float h[FEAT * CSTRIDE];
    for (int i = threadIdx.x; i < FEAT * CSTRIDE; i += 256) h[i] = 0.0f;
    int b = blockIdx.y;
    float bmax = __uint_as_float(bbox[b]);
    float thick = fmaxf(2.0f * bmax, 1e-5f);
    float inv_thick = 1.0f / thick;   // once per thread; per-point uses mul
    __syncthreads();

    const float4* base = (const float4*)(x + (size_t)b * NPTS * 6);
    int tid = blockIdx.x * 256 + threadIdx.x;   // 4096 threads per batch
    int k = threadIdx.x & (COPIES - 1);
    for (int i = tid; i < NPTS / 2; i += 4096) {
        float4 f0 = base[3 * i + 0];
        float4 f1 = base[3 * i + 1];
        float4 f2 = base[3 * i + 2];
        bin_point(h, k, f0.x, f0.y, f0.z, f0.w, f1.x, f1.y, bmax, inv_thick);
        bin_point(h, k, f1.z, f1.w, f2.x, f2.y, f2.z, f2.w, bmax, inv_thick);
    }
    __syncthreads();
    for (int v = threadIdx.x; v < FEAT; v += 256) {
        float sum = 0.0f;
        #pragma unroll
        for (int c = 0; c < COPIES; ++c) sum += h[v * CSTRIDE + c];
        unsafeAtomicAdd(&acc[b * FEAT + v], sum);
    }
}

// Pass 3: features + L2 normalize. grid B x 640 (one thread per feature).
__global__ __launch_bounds__(640) void k_final(const float* __restrict__ acc,
                                               float* __restrict__ out) {
    int b = blockIdx.x;
    int t = threadIdx.x;           // 0..639
    int cell = t / 10, j = t - cell * 10;
    float n = acc[b * FEAT + cell * 10];   // count for this cell
    float v = acc[b * FEAT + t];
    float fc = fmaxf(n, 1.0f);
    float up = 1.0f / sqrtf(fc);
    float val;
    if (j == 0)      val = 0.001f * n * up;
    else if (j < 4)  val = v * up;
    else             val = v / fc;

    // block reduction of sum(val^2) across 10 waves
    __shared__ float red[12];
    float s = val * val;
    for (int off = 32; off > 0; off >>= 1) s += __shfl_down(s, off, 64);
    if ((t & 63) == 0) red[t >> 6] = s;
    __syncthreads();
    if (t == 0) {
        float tot = 0.0f;
        #pragma unroll
        for (int w = 0; w < 10; ++w) tot += red[w];
        red[10] = fmaxf(sqrtf(tot), 1e-12f);
    }
    __syncthreads();
    out[b * FEAT + t] = val / red[10];
}

extern "C" void kernel_launch(void* const* d_in, const int* in_sizes, int n_in,
                              void* d_out, int out_size, void* d_ws, size_t ws_size,
                              hipStream_t stream) {
    const float* x = (const float*)d_in[0];
    float* out = (float*)d_out;
    unsigned int* bbox = (unsigned int*)d_ws;
    float* acc = (float*)((char*)d_ws + 256);

    // zero bbox + accumulators (ws is poisoned 0xAA before every launch)
    hipMemsetAsync(d_ws, 0, 256 + (size_t)BATCH * FEAT * 4, stream);

    dim3 grid(16, BATCH);
    k_bbox<<<grid, 256, 0, stream>>>(x, bbox);
    k_bin<<<grid, 256, 0, stream>>>(x, bbox, acc);
    k_final<<<BATCH, 640, 0, stream>>>(acc, out);
}

// Round 3
// 167.139 us; speedup vs baseline: 2.1573x; 2.1422x over previous
//
#include <hip/hip_runtime.h>

// HandcraftedPodExtractor: 3D cell binning + normalized feature vector.
// Input  x: (64, 65536, 6) fp32  [pos(3) | ori(3)] interleaved per point.
// Output  : (64, 640) fp32.
//
// R2 finding: fp atomicAdd AND unsafeAtomicAdd timed identically (214 us,
// VALUBusy 2.4%) -> both likely CAS loops (generic-pointer fp atomic).
// R3: NO float atomics anywhere. LDS histograms are int32 fixed-point
// (ds_add_u32 is always native); global flush is int64 atomicAdd (native).
//   count: +1 exact
//   offsets: round(off * 2^18)  (|off|<=0.1251 -> per-pt<2^15, blk-sum<2^27)
//   cov:     round(v  * 2^12)  (|v|<=~32     -> per-pt<2^18, blk-sum<2^31)
// Quantization error after /sqrt(freq) or /freq: ~1e-6, threshold 5.9e-3.
//
// ws layout:
//   [0,   256)            : per-batch bbox_max as uint bits (64 * 4B, padded)
//   [256, 256 + 327680)   : acc[B][640] int64

#define BATCH 64
#define NPTS 65536
#define FEAT 640          // 64 cells * 10 values
#define COPIES 16         // replicated LDS histograms (lane % 16)
#define CSTRIDE 17        // padded copy stride -> 16 distinct banks per slot
#define S_OFF 262144.0f   // 2^18
#define S_COV 4096.0f     // 2^12

__device__ __forceinline__ void bin_point(int* h, int k,
                                          float px, float py, float pz,
                                          float ox, float oy, float oz,
                                          float bmax, float inv_thick) {
    float sx = (px + bmax) * inv_thick;
    float sy = (py + bmax) * inv_thick;
    float sz = (pz + bmax) * inv_thick;
    int cx = (int)(sx * 4.0f); cx = cx < 0 ? 0 : (cx > 3 ? 3 : cx);
    int cy = (int)(sy * 4.0f); cy = cy < 0 ? 0 : (cy > 3 ? 3 : cy);
    int cz = (int)(sz * 4.0f); cz = cz < 0 ? 0 : (cz > 3 ? 3 : cz);
    int cell = (cx * 4 + cy) * 4 + cz;
    float offx = sx - (cx * 0.25f + 0.125f);
    float offy = sy - (cy * 0.25f + 0.125f);
    float offz = sz - (cz * 0.25f + 0.125f);
    int a = cell * (10 * CSTRIDE) + k;
    atomicAdd(&h[a + 0 * CSTRIDE], 1);
    atomicAdd(&h[a + 1 * CSTRIDE], __float2int_rn(offx * S_OFF));
    atomicAdd(&h[a + 2 * CSTRIDE], __float2int_rn(offy * S_OFF));
    atomicAdd(&h[a + 3 * CSTRIDE], __float2int_rn(offz * S_OFF));
    atomicAdd(&h[a + 4 * CSTRIDE], __float2int_rn(ox * ox * S_COV));
    atomicAdd(&h[a + 5 * CSTRIDE], __float2int_rn(ox * oy * S_COV));
    atomicAdd(&h[a + 6 * CSTRIDE], __float2int_rn(ox * oz * S_COV));
    atomicAdd(&h[a + 7 * CSTRIDE], __float2int_rn(oy * oy * S_COV));
    atomicAdd(&h[a + 8 * CSTRIDE], __float2int_rn(oy * oz * S_COV));
    atomicAdd(&h[a + 9 * CSTRIDE], __float2int_rn(oz * oz * S_COV));
}

// Pass 1: per-batch max|pos|. grid (16, B) x 256. Fully unrolled: 24 loads
// in flight before any consumption.
__global__ __launch_bounds__(256) void k_bbox(const float* __restrict__ x,
                                              unsigned int* __restrict__ bbox) {
    int b = blockIdx.y;
    const float4* base = (const float4*)(x + (size_t)b * NPTS * 6);
    int tid = blockIdx.x * 256 + threadIdx.x;   // 4096 threads per batch
    float m = 0.0f;
    #pragma unroll
    for (int it = 0; it < 8; ++it) {
        int i = tid + it * 4096;                // pair index < 32768
        float4 f0 = base[3 * i + 0];
        float4 f1 = base[3 * i + 1];
        float4 f2 = base[3 * i + 2];
        m = fmaxf(m, fabsf(f0.x)); m = fmaxf(m, fabsf(f0.y)); m = fmaxf(m, fabsf(f0.z));
        m = fmaxf(m, fabsf(f1.z)); m = fmaxf(m, fabsf(f1.w)); m = fmaxf(m, fabsf(f2.x));
    }
    for (int off = 32; off > 0; off >>= 1) m = fmaxf(m, __shfl_down(m, off, 64));
    __shared__ float s[4];
    if ((threadIdx.x & 63) == 0) s[threadIdx.x >> 6] = m;
    __syncthreads();
    if (threadIdx.x == 0) {
        m = fmaxf(fmaxf(s[0], s[1]), fmaxf(s[2], s[3]));
        atomicMax(&bbox[b], __float_as_uint(m));  // integer atomic: native
    }
}

// Pass 2: int32 histogram into 16 replicated LDS copies, int64 global flush.
// grid (16, B) x 256. LDS = 640*17*4 = 43520 B -> 3 blocks/CU.
__global__ __launch_bounds__(256) void k_bin(const float* __restrict__ x,
                                             const unsigned int* __restrict__ bbox,
                                             unsigned long long* __restrict__ acc) {
    __shared__ int h[FEAT * CSTRIDE];
    for (int i = threadIdx.x; i < FEAT * CSTRIDE; i += 256) h[i] = 0;
    int b = blockIdx.y;
    float bmax = __uint_as_float(bbox[b]);
    float thick = fmaxf(2.0f * bmax, 1e-5f);
    float inv_thick = 1.0f / thick;
    __syncthreads();

    const float4* base = (const float4*)(x + (size_t)b * NPTS * 6);
    int tid = blockIdx.x * 256 + threadIdx.x;   // 4096 threads per batch
    int k = threadIdx.x & (COPIES - 1);
    #pragma unroll
    for (int it = 0; it < 8; ++it) {
        int i = tid + it * 4096;
        float4 f0 = base[3 * i + 0];
        float4 f1 = base[3 * i + 1];
        float4 f2 = base[3 * i + 2];
        bin_point(h, k, f0.x, f0.y, f0.z, f0.w, f1.x, f1.y, bmax, inv_thick);
        bin_point(h, k, f1.z, f1.w, f2.x, f2.y, f2.z, f2.w, bmax, inv_thick);
    }
    __syncthreads();
    for (int v = threadIdx.x; v < FEAT; v += 256) {
        long long sum = 0;
        #pragma unroll
        for (int c = 0; c < COPIES; ++c) sum += (long long)h[v * CSTRIDE + c];
        atomicAdd(&acc[b * FEAT + v], (unsigned long long)sum); // native int64
    }
}

// Pass 3: features + L2 normalize. grid B x 640 (one thread per feature).
__global__ __launch_bounds__(640) void k_final(const unsigned long long* __restrict__ acc,
                                               float* __restrict__ out) {
    int b = blockIdx.x;
    int t = threadIdx.x;           // 0..639
    int cell = t / 10, j = t - cell * 10;
    long long ni = (long long)acc[b * FEAT + cell * 10];   // exact count
    long long vi = (long long)acc[b * FEAT + t];
    float n = (float)ni;
    float fc = fmaxf(n, 1.0f);
    float up = 1.0f / sqrtf(fc);
    float val;
    if (j == 0)      val = 0.001f * n * up;
    else if (j < 4)  val = ((float)vi * (1.0f / S_OFF)) * up;
    else             val = ((float)vi * (1.0f / S_COV)) / fc;

    // block reduction of sum(val^2) across 10 waves
    __shared__ float red[12];
    float s = val * val;
    for (int off = 32; off > 0; off >>= 1) s += __shfl_down(s, off, 64);
    if ((t & 63) == 0) red[t >> 6] = s;
    __syncthreads();
    if (t == 0) {
        float tot = 0.0f;
        #pragma unroll
        for (int w = 0; w < 10; ++w) tot += red[w];
        red[10] = fmaxf(sqrtf(tot), 1e-12f);
    }
    __syncthreads();
    out[b * FEAT + t] = val / red[10];
}

extern "C" void kernel_launch(void* const* d_in, const int* in_sizes, int n_in,
                              void* d_out, int out_size, void* d_ws, size_t ws_size,
                              hipStream_t stream) {
    const float* x = (const float*)d_in[0];
    float* out = (float*)d_out;
    unsigned int* bbox = (unsigned int*)d_ws;
    unsigned long long* acc = (unsigned long long*)((char*)d_ws + 256);

    // zero bbox + accumulators (ws is poisoned 0xAA before every launch)
    hipMemsetAsync(d_ws, 0, 256 + (size_t)BATCH * FEAT * 8, stream);

    dim3 grid(16, BATCH);
    k_bbox<<<grid, 256, 0, stream>>>(x, bbox);
    k_bin<<<grid, 256, 0, stream>>>(x, bbox, acc);
    k_final<<<BATCH, 640, 0, stream>>>(acc, out);
}

// Round 4
// 164.478 us; speedup vs baseline: 2.1922x; 1.0162x over previous
//
#include <hip/hip_runtime.h>

// HandcraftedPodExtractor: 3D cell binning + normalized feature vector.
// Input  x: (64, 65536, 6) fp32  [pos(3) | ori(3)] interleaved per point.
// Output  : (64, 640) fp32.
//
// R3 findings: int fixed-point LDS histogram (native ds_add_u32) cut k_bin
// 214->~25us; timed region includes ~90us of harness restore/poison (402MB
// fill @ 59us visible in profile). R4: consolidate — drop our memset
// dispatch. k_bbox zeroes acc with plain stores and writes per-block
// partial maxes (no atomicMax, no init needed); k_bin reduces the 16
// partials in registers. Kernel-boundary coherence guarantees visibility.
//
// Fixed-point scales:
//   offsets: round(off * 2^18)  (|off|<=~0.13 -> per-pt<2^15, blk-sum<2^27)
//   cov:     round(v  * 2^12)  (per-pt<2^18 at 5.6-sigma, blk-sum<2^31)
// Output quantization error ~1e-6..1e-4, threshold 5.9e-3.
//
// ws layout:
//   [0,    4096)           : part_max[B*16] as uint bits (nonneg floats)
//   [4096, 4096 + 327680)  : acc[B][640] int64

#define BATCH 64
#define NPTS 65536
#define FEAT 640          // 64 cells * 10 values
#define COPIES 16         // replicated LDS histograms (lane % 16)
#define CSTRIDE 17        // padded copy stride -> 16 distinct banks per slot
#define S_OFF 262144.0f   // 2^18
#define S_COV 4096.0f     // 2^12

__device__ __forceinline__ void bin_point(int* h, int k,
                                          float px, float py, float pz,
                                          float ox, float oy, float oz,
                                          float bmax, float inv_thick) {
    float sx = (px + bmax) * inv_thick;
    float sy = (py + bmax) * inv_thick;
    float sz = (pz + bmax) * inv_thick;
    int cx = (int)(sx * 4.0f); cx = cx < 0 ? 0 : (cx > 3 ? 3 : cx);
    int cy = (int)(sy * 4.0f); cy = cy < 0 ? 0 : (cy > 3 ? 3 : cy);
    int cz = (int)(sz * 4.0f); cz = cz < 0 ? 0 : (cz > 3 ? 3 : cz);
    int cell = (cx * 4 + cy) * 4 + cz;
    float offx = sx - (cx * 0.25f + 0.125f);
    float offy = sy - (cy * 0.25f + 0.125f);
    float offz = sz - (cz * 0.25f + 0.125f);
    int a = cell * (10 * CSTRIDE) + k;
    atomicAdd(&h[a + 0 * CSTRIDE], 1);
    atomicAdd(&h[a + 1 * CSTRIDE], __float2int_rn(offx * S_OFF));
    atomicAdd(&h[a + 2 * CSTRIDE], __float2int_rn(offy * S_OFF));
    atomicAdd(&h[a + 3 * CSTRIDE], __float2int_rn(offz * S_OFF));
    atomicAdd(&h[a + 4 * CSTRIDE], __float2int_rn(ox * ox * S_COV));
    atomicAdd(&h[a + 5 * CSTRIDE], __float2int_rn(ox * oy * S_COV));
    atomicAdd(&h[a + 6 * CSTRIDE], __float2int_rn(ox * oz * S_COV));
    atomicAdd(&h[a + 7 * CSTRIDE], __float2int_rn(oy * oy * S_COV));
    atomicAdd(&h[a + 8 * CSTRIDE], __float2int_rn(oy * oz * S_COV));
    atomicAdd(&h[a + 9 * CSTRIDE], __float2int_rn(oz * oz * S_COV));
}

// Pass 1: per-batch max|pos| -> partial maxes; also zero-init acc.
// grid (16, B) x 256.
__global__ __launch_bounds__(256) void k_bbox(const float* __restrict__ x,
                                              unsigned int* __restrict__ part,
                                              unsigned long long* __restrict__ acc) {
    int b = blockIdx.y;
    int fb = b * 16 + blockIdx.x;             // flat block id 0..1023
    // zero acc: 40960 ull / 1024 blocks = 40 per block (plain stores;
    // kernel-boundary coherence makes them visible to k_bin's atomics)
    if (threadIdx.x < 40) acc[fb * 40 + threadIdx.x] = 0ULL;

    const float4* base = (const float4*)(x + (size_t)b * NPTS * 6);
    int tid = blockIdx.x * 256 + threadIdx.x;   // 4096 threads per batch
    float m = 0.0f;
    #pragma unroll
    for (int it = 0; it < 8; ++it) {
        int i = tid + it * 4096;                // pair index < 32768
        float4 f0 = base[3 * i + 0];
        float4 f1 = base[3 * i + 1];
        float4 f2 = base[3 * i + 2];
        m = fmaxf(m, fabsf(f0.x)); m = fmaxf(m, fabsf(f0.y)); m = fmaxf(m, fabsf(f0.z));
        m = fmaxf(m, fabsf(f1.z)); m = fmaxf(m, fabsf(f1.w)); m = fmaxf(m, fabsf(f2.x));
    }
    for (int off = 32; off > 0; off >>= 1) m = fmaxf(m, __shfl_down(m, off, 64));
    __shared__ float s[4];
    if ((threadIdx.x & 63) == 0) s[threadIdx.x >> 6] = m;
    __syncthreads();
    if (threadIdx.x == 0) {
        m = fmaxf(fmaxf(s[0], s[1]), fmaxf(s[2], s[3]));
        part[fb] = __float_as_uint(m);          // plain store, no init needed
    }
}

// Pass 2: int32 histogram into 16 replicated LDS copies, int64 global flush.
// grid (16, B) x 256. LDS = 640*17*4 = 43520 B -> 3 blocks/CU.
__global__ __launch_bounds__(256) void k_bin(const float* __restrict__ x,
                                             const unsigned int* __restrict__ part,
                                             unsigned long long* __restrict__ acc) {
    __shared__ int h[FEAT * CSTRIDE];
    for (int i = threadIdx.x; i < FEAT * CSTRIDE; i += 256) h[i] = 0;
    int b = blockIdx.y;
    // reduce the 16 partial maxes (uint compare == float compare for >=0)
    unsigned int um = 0u;
    #pragma unroll
    for (int p = 0; p < 16; ++p) um = um > part[b * 16 + p] ? um : part[b * 16 + p];
    float bmax = __uint_as_float(um);
    float thick = fmaxf(2.0f * bmax, 1e-5f);
    float inv_thick = 1.0f / thick;
    __syncthreads();

    const float4* base = (const float4*)(x + (size_t)b * NPTS * 6);
    int tid = blockIdx.x * 256 + threadIdx.x;   // 4096 threads per batch
    int k = threadIdx.x & (COPIES - 1);
    #pragma unroll
    for (int it = 0; it < 8; ++it) {
        int i = tid + it * 4096;
        float4 f0 = base[3 * i + 0];
        float4 f1 = base[3 * i + 1];
        float4 f2 = base[3 * i + 2];
        bin_point(h, k, f0.x, f0.y, f0.z, f0.w, f1.x, f1.y, bmax, inv_thick);
        bin_point(h, k, f1.z, f1.w, f2.x, f2.y, f2.z, f2.w, bmax, inv_thick);
    }
    __syncthreads();
    for (int v = threadIdx.x; v < FEAT; v += 256) {
        long long sum = 0;
        #pragma unroll
        for (int c = 0; c < COPIES; ++c) sum += (long long)h[v * CSTRIDE + c];
        atomicAdd(&acc[b * FEAT + v], (unsigned long long)sum); // native int64
    }
}

// Pass 3: features + L2 normalize. grid B x 640 (one thread per feature).
__global__ __launch_bounds__(640) void k_final(const unsigned long long* __restrict__ acc,
                                               float* __restrict__ out) {
    int b = blockIdx.x;
    int t = threadIdx.x;           // 0..639
    int cell = t / 10, j = t - cell * 10;
    long long ni = (long long)acc[b * FEAT + cell * 10];   // exact count
    long long vi = (long long)acc[b * FEAT + t];
    float n = (float)ni;
    float fc = fmaxf(n, 1.0f);
    float up = 1.0f / sqrtf(fc);
    float val;
    if (j == 0)      val = 0.001f * n * up;
    else if (j < 4)  val = ((float)vi * (1.0f / S_OFF)) * up;
    else             val = ((float)vi * (1.0f / S_COV)) / fc;

    // block reduction of sum(val^2) across 10 waves
    __shared__ float red[12];
    float s = val * val;
    for (int off = 32; off > 0; off >>= 1) s += __shfl_down(s, off, 64);
    if ((t & 63) == 0) red[t >> 6] = s;
    __syncthreads();
    if (t == 0) {
        float tot = 0.0f;
        #pragma unroll
        for (int w = 0; w < 10; ++w) tot += red[w];
        red[10] = fmaxf(sqrtf(tot), 1e-12f);
    }
    __syncthreads();
    out[b * FEAT + t] = val / red[10];
}

extern "C" void kernel_launch(void* const* d_in, const int* in_sizes, int n_in,
                              void* d_out, int out_size, void* d_ws, size_t ws_size,
                              hipStream_t stream) {
    const float* x = (const float*)d_in[0];
    float* out = (float*)d_out;
    unsigned int* part = (unsigned int*)d_ws;
    unsigned long long* acc = (unsigned long long*)((char*)d_ws + 4096);

    dim3 grid(16, BATCH);
    k_bbox<<<grid, 256, 0, stream>>>(x, part, acc);
    k_bin<<<grid, 256, 0, stream>>>(x, part, acc);
    k_final<<<BATCH, 640, 0, stream>>>(acc, out);
}